// Round 2
// baseline (653.183 us; speedup 1.0000x reference)
//
#include <hip/hip_runtime.h>

#define N_NODES 100000
#define N_EDGES 1600000
#define D 128
#define SCAN_BLOCKS 391   // ceil(N_NODES / 256)
#define NBUCK 98          // ceil(N_NODES / 1024), bucket = dst >> 10

typedef __attribute__((ext_vector_type(8))) short bf16x8;
typedef __attribute__((ext_vector_type(4))) float f32x4;
typedef unsigned long long u64;

__device__ __forceinline__ float b2f_lo(unsigned int u) {
    return __builtin_bit_cast(float, u << 16);
}
__device__ __forceinline__ float b2f_hi(unsigned int u) {
    return __builtin_bit_cast(float, u & 0xFFFF0000u);
}
__device__ __forceinline__ unsigned short f2b(float f) {
    unsigned int u = __builtin_bit_cast(unsigned int, f);
    u += 0x7FFFu + ((u >> 16) & 1u);
    return (unsigned short)(u >> 16);
}

// ---------------- prep: zero scratch + convert weights + convert x, one dispatch ----------------

__global__ __launch_bounds__(256) void prep_kernel(
    const float* __restrict__ x, unsigned short* __restrict__ xb,
    const float* __restrict__ W0, const float* __restrict__ W1_, const float* __restrict__ W2_,
    const float* __restrict__ W3, const float* __restrict__ W4, const float* __restrict__ W5,
    unsigned short* __restrict__ T0, unsigned short* __restrict__ T1_,
    unsigned short* __restrict__ T2_, unsigned short* __restrict__ T3,
    unsigned short* __restrict__ T4, unsigned short* __restrict__ T5,
    uint4* __restrict__ dob4) {
    int blk = blockIdx.x;
    if (blk < 384) {
        const float* W;
        unsigned short* T;
        switch (blk >> 6) {
            case 0: W = W0; T = T0; break;
            case 1: W = W1_; T = T1_; break;
            case 2: W = W2_; T = T2_; break;
            case 3: W = W3; T = T3; break;
            case 4: W = W4; T = T4; break;
            default: W = W5; T = T5; break;
        }
        int i = (blk & 63) * 256 + threadIdx.x;   // 0..16383
        int k = i >> 7, n = i & 127;
        T[n * 128 + k] = f2b(W[i]);               // [k][n] fp32 -> [n][k] bf16
    } else if (blk < 12884) {
        int i = (blk - 384) * 256 + threadIdx.x;  // float4 chunks, 3200000 total
        if (i < 3200000) {
            float4 v = ((const float4*)x)[i];
            ushort4 o;
            o.x = f2b(v.x); o.y = f2b(v.y); o.z = f2b(v.z); o.w = f2b(v.w);
            ((ushort4*)xb)[i] = o;
        }
    } else {
        int i = (blk - 12884) * 256 + threadIdx.x;  // zero d_out scratch head [0, 806144)
        if (i < 50384) {
            uint4 z = {0u, 0u, 0u, 0u};
            dob4[i] = z;
        }
    }
}

// ---------------- CSR build ----------------

__global__ void hist_kernel(const int* __restrict__ dst, int* __restrict__ deg, int n) {
    int i = blockIdx.x * blockDim.x + threadIdx.x;
    if (i < n) atomicAdd(&deg[dst[i]], 1);
}

__global__ __launch_bounds__(256) void block_sum_kernel(const int* __restrict__ deg,
                                                        int* __restrict__ bsum) {
    __shared__ int s[256];
    int i = blockIdx.x * 256 + threadIdx.x;
    int v = (i < N_NODES) ? deg[i] : 0;
    s[threadIdx.x] = v;
    __syncthreads();
#pragma unroll
    for (int d = 128; d > 0; d >>= 1) {
        if (threadIdx.x < d) s[threadIdx.x] += s[threadIdx.x + d];
        __syncthreads();
    }
    if (threadIdx.x == 0) bsum[blockIdx.x] = s[0];
}

__global__ __launch_bounds__(512) void scan_bsum_kernel(const int* __restrict__ bsum,
                                                        int* __restrict__ bpref,
                                                        int* __restrict__ off) {
    __shared__ int s[512];
    int tid = threadIdx.x;
    int v = (tid < SCAN_BLOCKS) ? bsum[tid] : 0;
    s[tid] = v;
    __syncthreads();
#pragma unroll
    for (int d = 1; d < 512; d <<= 1) {
        int t = (tid >= d) ? s[tid - d] : 0;
        __syncthreads();
        s[tid] += t;
        __syncthreads();
    }
    if (tid < SCAN_BLOCKS) bpref[tid] = s[tid] - v;   // exclusive
    if (tid == 0) off[N_NODES] = N_EDGES;
}

__global__ __launch_bounds__(256) void block_scan_kernel(const int* __restrict__ deg,
                                                         const int* __restrict__ bpref,
                                                         int* __restrict__ off) {
    __shared__ int s[256];
    int i = blockIdx.x * 256 + threadIdx.x;
    int tid = threadIdx.x;
    int v = (i < N_NODES) ? deg[i] : 0;
    s[tid] = v;
    __syncthreads();
#pragma unroll
    for (int d = 1; d < 256; d <<= 1) {
        int t = (tid >= d) ? s[tid - d] : 0;
        __syncthreads();
        s[tid] += t;
        __syncthreads();
    }
    if (i < N_NODES) off[i] = bpref[blockIdx.x] + s[tid] - v;   // exclusive
}

// Bin edges into bucket-ordered packed (dst<<32|src) slabs. Slab base = off[b<<10].
__global__ __launch_bounds__(256) void bin_kernel(const int* __restrict__ src,
                                                  const int* __restrict__ dst,
                                                  const int* __restrict__ off,
                                                  int* __restrict__ bcur,
                                                  u64* __restrict__ ebuf) {
    __shared__ int h[NBUCK];
    __shared__ int base[NBUCK];
    int tid = threadIdx.x;
    if (tid < NBUCK) h[tid] = 0;
    __syncthreads();
    int e0 = blockIdx.x * 2048;
    int myd[8], mys[8];
#pragma unroll
    for (int i = 0; i < 8; i++) {
        int e = e0 + tid + i * 256;
        int dv = (e < N_EDGES) ? dst[e] : -1;
        myd[i] = dv;
        mys[i] = (e < N_EDGES) ? src[e] : 0;
        if (dv >= 0) atomicAdd(&h[dv >> 10], 1);
    }
    __syncthreads();
    if (tid < NBUCK) {
        int c = h[tid];
        base[tid] = (c > 0) ? (off[tid << 10] + atomicAdd(&bcur[tid], c)) : 0;
        h[tid] = 0;
    }
    __syncthreads();
#pragma unroll
    for (int i = 0; i < 8; i++) {
        int dv = myd[i];
        if (dv >= 0) {
            int b = dv >> 10;
            int p = base[b] + atomicAdd(&h[b], 1);
            ebuf[p] = ((u64)(unsigned int)dv << 32) | (unsigned int)mys[i];
        }
    }
}

// Sequential bucket-ordered scatter (R5 form — restored after R8's src-banding
// regression: banding spread each csr line's writes over 64 temporal windows,
// 16x write amplification. Sequential emission keeps writes in an L2-resident
// ~64KB window per bucket -> amplification ~1).
__global__ __launch_bounds__(256) void scatter2_kernel(const u64* __restrict__ ebuf,
                                                       const int* __restrict__ off,
                                                       int* __restrict__ cnt,
                                                       int* __restrict__ csr) {
    int i = blockIdx.x * 256 + threadIdx.x;
    if (i < N_EDGES) {
        u64 e = ebuf[i];
        int dv = (int)(e >> 32);
        int p = off[dv] + atomicAdd(&cnt[dv], 1);
        csr[p] = (int)(e & 0xFFFFFFFFu);
    }
}

// Sort each node's adjacency list by src (ascending). With sorted lists, all
// concurrently-resident agg waves at edge-position k gather from src ~ (k/deg)*N
// +- ~10K nodes, shrinking the instantaneous gather working set from 25.6 MB to
// a few MB (L2-sized) -> higher L2 hit rate on the 410 MB gather stream.
// 128 thr/block: 128*49*4 = 25,088 B LDS (256 was 200KB -> over the LDS cap,
// compile failure last round).
__global__ __launch_bounds__(128) void sort_adj_kernel(const int* __restrict__ off,
                                                       int* __restrict__ csr) {
    __shared__ int sb[128 * 49];
    int node = blockIdx.x * 128 + threadIdx.x;
    if (node >= N_NODES) return;
    int s = off[node];
    int n = off[node + 1] - s;
    if (n <= 1 || n > 49) return;   // n>49: P~0 (mean deg 16); leave unsorted, still correct
    int* a = &sb[threadIdx.x * 49];
    for (int i = 0; i < n; i++) a[i] = csr[s + i];
    for (int i = 1; i < n; i++) {
        int v = a[i], j = i - 1;
        while (j >= 0 && a[j] > v) { a[j + 1] = a[j]; j--; }
        a[j + 1] = v;
    }
    for (int i = 0; i < n; i++) csr[s + i] = a[i];
}

// ---------------- aggregation: t[i] = x[i] + sum_{j in N_in(i)} x[j]  (bf16 in/out) ----------------
// unroll-8 main loop (was 4): VGPR=12 leaves headroom; doubling in-flight gathers
// attacks the latency-bound regime (VALUBusy 35%, no pipe saturated).

__global__ __launch_bounds__(256) void agg_bf16(const unsigned int* __restrict__ xb,
                                                const int* __restrict__ off,
                                                const int* __restrict__ csr,
                                                unsigned int* __restrict__ t) {
    int node = blockIdx.x * 4 + (threadIdx.x >> 6);
    if (node >= N_NODES) return;
    int lane = threadIdx.x & 63;
    unsigned int v = xb[(size_t)node * 64 + lane];
    float ax = b2f_lo(v), ay = b2f_hi(v);
    int e = off[node + 1];
    int k = off[node];
    for (; k + 8 <= e; k += 8) {
        int n0 = csr[k + 0], n1 = csr[k + 1], n2 = csr[k + 2], n3 = csr[k + 3];
        int n4 = csr[k + 4], n5 = csr[k + 5], n6 = csr[k + 6], n7 = csr[k + 7];
        unsigned int g0 = xb[(size_t)n0 * 64 + lane];
        unsigned int g1 = xb[(size_t)n1 * 64 + lane];
        unsigned int g2 = xb[(size_t)n2 * 64 + lane];
        unsigned int g3 = xb[(size_t)n3 * 64 + lane];
        unsigned int g4 = xb[(size_t)n4 * 64 + lane];
        unsigned int g5 = xb[(size_t)n5 * 64 + lane];
        unsigned int g6 = xb[(size_t)n6 * 64 + lane];
        unsigned int g7 = xb[(size_t)n7 * 64 + lane];
        ax += b2f_lo(g0) + b2f_lo(g1) + b2f_lo(g2) + b2f_lo(g3)
            + b2f_lo(g4) + b2f_lo(g5) + b2f_lo(g6) + b2f_lo(g7);
        ay += b2f_hi(g0) + b2f_hi(g1) + b2f_hi(g2) + b2f_hi(g3)
            + b2f_hi(g4) + b2f_hi(g5) + b2f_hi(g6) + b2f_hi(g7);
    }
    if (k + 4 <= e) {
        int n0 = csr[k + 0], n1 = csr[k + 1], n2 = csr[k + 2], n3 = csr[k + 3];
        unsigned int g0 = xb[(size_t)n0 * 64 + lane];
        unsigned int g1 = xb[(size_t)n1 * 64 + lane];
        unsigned int g2 = xb[(size_t)n2 * 64 + lane];
        unsigned int g3 = xb[(size_t)n3 * 64 + lane];
        ax += b2f_lo(g0) + b2f_lo(g1) + b2f_lo(g2) + b2f_lo(g3);
        ay += b2f_hi(g0) + b2f_hi(g1) + b2f_hi(g2) + b2f_hi(g3);
        k += 4;
    }
    for (; k < e; k++) {
        unsigned int g = xb[(size_t)csr[k] * 64 + lane];
        ax += b2f_lo(g);
        ay += b2f_hi(g);
    }
    t[(size_t)node * 64 + lane] = (unsigned int)f2b(ax) | ((unsigned int)f2b(ay) << 16);
}

// ---------------- fused MLP: y = relu(relu(t @ W1 + b1) @ W2 + b2) ----------------
// 2 row-strips (32 rows) per wave: one W-fragment load feeds MFMAs of both strips,
// halving per-wave L2 weight traffic (was ~400MB/dispatch). Per-wave LDS 8704 B
// (2 bf16 u-strips; f32 epilogue reuses the same 8704 B region).

template <bool OUT_F32>
__global__ __launch_bounds__(256) void mlp_mfma(const unsigned short* __restrict__ A,
                                                const unsigned short* __restrict__ W1t,
                                                const float* __restrict__ bias1,
                                                const unsigned short* __restrict__ W2t,
                                                const float* __restrict__ bias2,
                                                void* __restrict__ out) {
    __shared__ char smem[4 * 8704];
    int tid = threadIdx.x;
    int wave = tid >> 6, lane = tid & 63;
    int quad = lane >> 4, mr = lane & 15;
    int m_base = blockIdx.x * 128 + wave * 32;
    int m0 = m_base + mr;       if (m0 >= N_NODES) m0 = N_NODES - 1;
    int m1 = m_base + 16 + mr;  if (m1 >= N_NODES) m1 = N_NODES - 1;

    unsigned short* ust = (unsigned short*)(smem + wave * 8704);  // strip0 @0, strip1 @2176 shorts

    // ---- GEMM1: u = relu(t @ W1 + b1), both strips ----
    bf16x8 a0[4], a1[4];
#pragma unroll
    for (int kc = 0; kc < 4; kc++) {
        a0[kc] = *(const bf16x8*)(A + (size_t)m0 * D + kc * 32 + quad * 8);
        a1[kc] = *(const bf16x8*)(A + (size_t)m1 * D + kc * 32 + quad * 8);
    }

    f32x4 acc0[8], acc1[8];
#pragma unroll
    for (int nt = 0; nt < 8; nt++) { acc0[nt] = (f32x4)0.0f; acc1[nt] = (f32x4)0.0f; }
#pragma unroll
    for (int nt = 0; nt < 8; nt++) {
        const unsigned short* wp = W1t + (size_t)(nt * 16 + mr) * D + quad * 8;
#pragma unroll
        for (int kc = 0; kc < 4; kc++) {
            bf16x8 b = *(const bf16x8*)(wp + kc * 32);
            acc0[nt] = __builtin_amdgcn_mfma_f32_16x16x32_bf16(a0[kc], b, acc0[nt], 0, 0, 0);
            acc1[nt] = __builtin_amdgcn_mfma_f32_16x16x32_bf16(a1[kc], b, acc1[nt], 0, 0, 0);
        }
    }
    // C layout: col(n) = mr, row(m in strip) = quad*4 + r
#pragma unroll
    for (int nt = 0; nt < 8; nt++) {
        float bv = bias1[nt * 16 + mr];
#pragma unroll
        for (int r = 0; r < 4; r++) {
            ust[(quad * 4 + r) * 136 + nt * 16 + mr] = f2b(fmaxf(acc0[nt][r] + bv, 0.0f));
            ust[2176 + (quad * 4 + r) * 136 + nt * 16 + mr] = f2b(fmaxf(acc1[nt][r] + bv, 0.0f));
        }
    }

    // ---- GEMM2: y = relu(u @ W2 + b2), both strips ----
#pragma unroll
    for (int kc = 0; kc < 4; kc++) {
        a0[kc] = *(const bf16x8*)&ust[mr * 136 + kc * 32 + quad * 8];
        a1[kc] = *(const bf16x8*)&ust[2176 + mr * 136 + kc * 32 + quad * 8];
    }
#pragma unroll
    for (int nt = 0; nt < 8; nt++) { acc0[nt] = (f32x4)0.0f; acc1[nt] = (f32x4)0.0f; }
#pragma unroll
    for (int nt = 0; nt < 8; nt++) {
        const unsigned short* wp = W2t + (size_t)(nt * 16 + mr) * D + quad * 8;
#pragma unroll
        for (int kc = 0; kc < 4; kc++) {
            bf16x8 b = *(const bf16x8*)(wp + kc * 32);
            acc0[nt] = __builtin_amdgcn_mfma_f32_16x16x32_bf16(a0[kc], b, acc0[nt], 0, 0, 0);
            acc1[nt] = __builtin_amdgcn_mfma_f32_16x16x32_bf16(a1[kc], b, acc1[nt], 0, 0, 0);
        }
    }

    // ---- epilogue: stage each strip in LDS, coalesced store (u-strips dead now) ----
    if (OUT_F32) {
        float* st = (float*)ust;   // 16 x 132 f32 = 8448 B, fits in the 8704 B wave region
        const int S = 132;
        float* op = (float*)out;
#pragma unroll
        for (int s = 0; s < 2; s++) {
#pragma unroll
            for (int nt = 0; nt < 8; nt++) {
                float bv = bias2[nt * 16 + mr];
#pragma unroll
                for (int r = 0; r < 4; r++) {
                    float v = s ? acc1[nt][r] : acc0[nt][r];
                    st[(quad * 4 + r) * S + nt * 16 + mr] = fmaxf(v + bv, 0.0f);
                }
            }
#pragma unroll
            for (int it = 0; it < 8; it++) {
                int linear = lane + it * 64;
                int row = linear >> 5, col = (linear & 31) << 2;
                int gm = m_base + s * 16 + row;
                if (gm < N_NODES) {
                    float4 val = *(float4*)&st[row * S + col];
                    *(float4*)(op + (size_t)gm * D + col) = val;
                }
            }
        }
    } else {
        const int S = 136;
        unsigned short* op = (unsigned short*)out;
#pragma unroll
        for (int s = 0; s < 2; s++) {
            unsigned short* st = ust + s * 2176;
#pragma unroll
            for (int nt = 0; nt < 8; nt++) {
                float bv = bias2[nt * 16 + mr];
#pragma unroll
                for (int r = 0; r < 4; r++) {
                    float v = s ? acc1[nt][r] : acc0[nt][r];
                    st[(quad * 4 + r) * S + nt * 16 + mr] = f2b(fmaxf(v + bv, 0.0f));
                }
            }
#pragma unroll
            for (int it = 0; it < 4; it++) {
                int linear = lane + it * 64;
                int row = linear >> 4, col = (linear & 15) << 3;
                int gm = m_base + s * 16 + row;
                if (gm < N_NODES) {
                    uint4 val = *(uint4*)&st[row * S + col];
                    *(uint4*)(op + (size_t)gm * D + col) = val;
                }
            }
        }
    }
}

// ---------------- launch ----------------

extern "C" void kernel_launch(void* const* d_in, const int* in_sizes, int n_in,
                              void* d_out, int out_size, void* d_ws, size_t ws_size,
                              hipStream_t stream) {
    const float* x = (const float*)d_in[0];
    const int* ei = (const int*)d_in[1];
    const int* srcv = ei;
    const int* dstv = ei + N_EDGES;
    const float* W1[3] = {(const float*)d_in[2], (const float*)d_in[6], (const float*)d_in[10]};
    const float* b1[3] = {(const float*)d_in[3], (const float*)d_in[7], (const float*)d_in[11]};
    const float* W2[3] = {(const float*)d_in[4], (const float*)d_in[8], (const float*)d_in[12]};
    const float* b2[3] = {(const float*)d_in[5], (const float*)d_in[9], (const float*)d_in[13]};

    // ws layout (high-water 58400256):
    char* ws = (char*)d_ws;
    int* off = (int*)ws;                                    // (N+1) ints
    unsigned short* Wt[6];                                  // 6 x 32KB @ 400128
    for (int i = 0; i < 6; i++) Wt[i] = (unsigned short*)(ws + 400128 + i * 32768);
    int* csr = (int*)(ws + 800256);                         // E ints (ends 7200256)
    unsigned short* xb = (unsigned short*)(ws + 7200256);   // N*D bf16 (ends 32800256)
    unsigned short* P  = (unsigned short*)(ws + 32800256);  // N*D bf16 (ends 58400256)

    // d_out scratch (dead before the final MLP overwrites all of d_out):
    char* dob = (char*)d_out;
    int* deg   = (int*)(dob + 4096);        // N ints
    int* cnt2  = (int*)(dob + 404096);      // N ints
    int* bcur  = (int*)(dob + 804096);      // NBUCK ints
    int* bsum  = (int*)(dob + 806912);      // SCAN_BLOCKS ints
    int* bpref = (int*)(dob + 808960);      // SCAN_BLOCKS ints
    u64* ebuf  = (u64*)(dob + 1048576);     // E u64 = 12.8MB

    // --- prep: zero d_out scratch head + convert weights + convert x ---
    prep_kernel<<<13082, 256, 0, stream>>>(
        x, xb,
        W1[0], W2[0], W1[1], W2[1], W1[2], W2[2],
        Wt[0], Wt[1], Wt[2], Wt[3], Wt[4], Wt[5],
        (uint4*)dob);

    // --- CSR build (once; reused by all 3 layers) ---
    hist_kernel<<<(N_EDGES + 255) / 256, 256, 0, stream>>>(dstv, deg, N_EDGES);
    block_sum_kernel<<<SCAN_BLOCKS, 256, 0, stream>>>(deg, bsum);
    scan_bsum_kernel<<<1, 512, 0, stream>>>(bsum, bpref, off);
    block_scan_kernel<<<SCAN_BLOCKS, 256, 0, stream>>>(deg, bpref, off);
    bin_kernel<<<782, 256, 0, stream>>>(srcv, dstv, off, bcur, ebuf);
    scatter2_kernel<<<(N_EDGES + 255) / 256, 256, 0, stream>>>(ebuf, off, cnt2, csr);
    sort_adj_kernel<<<(N_NODES + 127) / 128, 128, 0, stream>>>(off, csr);

    const int agg_grid = 25000;                        // 4 nodes/block
    const int mlp_grid = (N_NODES + 127) / 128;        // 782 (2 strips/wave)

    // layer 0: agg xb->P, mlp P->xb
    agg_bf16<<<agg_grid, 256, 0, stream>>>((const unsigned int*)xb, off, csr, (unsigned int*)P);
    mlp_mfma<false><<<mlp_grid, 256, 0, stream>>>(P, Wt[0], b1[0], Wt[1], b2[0], xb);
    // layer 1
    agg_bf16<<<agg_grid, 256, 0, stream>>>((const unsigned int*)xb, off, csr, (unsigned int*)P);
    mlp_mfma<false><<<mlp_grid, 256, 0, stream>>>(P, Wt[2], b1[1], Wt[3], b2[1], xb);
    // layer 2
    agg_bf16<<<agg_grid, 256, 0, stream>>>((const unsigned int*)xb, off, csr, (unsigned int*)P);
    mlp_mfma<true><<<mlp_grid, 256, 0, stream>>>(P, Wt[4], b1[2], Wt[5], b2[2], d_out);
}

// Round 3
// 529.717 us; speedup vs baseline: 1.2331x; 1.2331x over previous
//
#include <hip/hip_runtime.h>

#define N_NODES 100000
#define N_EDGES 1600000
#define D 128
#define NBUCK 98          // ceil(N_NODES / 1024), bucket = dst >> 10
#define CAP 20480         // slab capacity per bucket: mean 16384, sigma~127 -> +32 sigma

typedef __attribute__((ext_vector_type(8))) short bf16x8;
typedef __attribute__((ext_vector_type(4))) float f32x4;
typedef unsigned long long u64;

__device__ __forceinline__ float b2f_lo(unsigned int u) {
    return __builtin_bit_cast(float, u << 16);
}
__device__ __forceinline__ float b2f_hi(unsigned int u) {
    return __builtin_bit_cast(float, u & 0xFFFF0000u);
}
__device__ __forceinline__ unsigned short f2b(float f) {
    unsigned int u = __builtin_bit_cast(unsigned int, f);
    u += 0x7FFFu + ((u >> 16) & 1u);
    return (unsigned short)(u >> 16);
}

// ---------------- prep: zero scratch + convert weights + convert x, one dispatch ----------------

__global__ __launch_bounds__(256) void prep_kernel(
    const float* __restrict__ x, unsigned short* __restrict__ xb,
    const float* __restrict__ W0, const float* __restrict__ W1_, const float* __restrict__ W2_,
    const float* __restrict__ W3, const float* __restrict__ W4, const float* __restrict__ W5,
    unsigned short* __restrict__ T0, unsigned short* __restrict__ T1_,
    unsigned short* __restrict__ T2_, unsigned short* __restrict__ T3,
    unsigned short* __restrict__ T4, unsigned short* __restrict__ T5,
    uint4* __restrict__ dob4) {
    int blk = blockIdx.x;
    if (blk < 384) {
        const float* W;
        unsigned short* T;
        switch (blk >> 6) {
            case 0: W = W0; T = T0; break;
            case 1: W = W1_; T = T1_; break;
            case 2: W = W2_; T = T2_; break;
            case 3: W = W3; T = T3; break;
            case 4: W = W4; T = T4; break;
            default: W = W5; T = T5; break;
        }
        int i = (blk & 63) * 256 + threadIdx.x;   // 0..16383
        int k = i >> 7, n = i & 127;
        T[n * 128 + k] = f2b(W[i]);               // [k][n] fp32 -> [n][k] bf16
    } else if (blk < 12884) {
        int i = (blk - 384) * 256 + threadIdx.x;  // float4 chunks, 3200000 total
        if (i < 3200000) {
            float4 v = ((const float4*)x)[i];
            ushort4 o;
            o.x = f2b(v.x); o.y = f2b(v.y); o.z = f2b(v.z); o.w = f2b(v.w);
            ((ushort4*)xb)[i] = o;
        }
    } else {
        int i = (blk - 12884) * 256 + threadIdx.x;  // zero d_out scratch head [0, 4096) = bcur
        if (i < 256) {
            uint4 z = {0u, 0u, 0u, 0u};
            dob4[i] = z;
        }
    }
}

// ---------------- CSR build (bucket-local, LDS atomics only) ----------------

// Bin edges into fixed-stride bucket slabs: slab b = ebuf[b*CAP ...]. No off dependency.
__global__ __launch_bounds__(256) void bin_kernel(const int* __restrict__ src,
                                                  const int* __restrict__ dst,
                                                  int* __restrict__ bcur,
                                                  u64* __restrict__ ebuf) {
    __shared__ int h[NBUCK];
    __shared__ int base[NBUCK];
    int tid = threadIdx.x;
    if (tid < NBUCK) h[tid] = 0;
    __syncthreads();
    int e0 = blockIdx.x * 2048;
    int myd[8], mys[8];
#pragma unroll
    for (int i = 0; i < 8; i++) {
        int e = e0 + tid + i * 256;
        int dv = (e < N_EDGES) ? dst[e] : -1;
        myd[i] = dv;
        mys[i] = (e < N_EDGES) ? src[e] : 0;
        if (dv >= 0) atomicAdd(&h[dv >> 10], 1);
    }
    __syncthreads();
    if (tid < NBUCK) {
        int c = h[tid];
        base[tid] = (c > 0) ? (tid * CAP + atomicAdd(&bcur[tid], c)) : 0;
        h[tid] = 0;
    }
    __syncthreads();
#pragma unroll
    for (int i = 0; i < 8; i++) {
        int dv = myd[i];
        if (dv >= 0) {
            int b = dv >> 10;
            int p = base[b] + atomicAdd(&h[b], 1);
            if (p < (b + 1) * CAP)
                ebuf[p] = ((u64)(unsigned int)dv << 32) | (unsigned int)mys[i];
        }
    }
}

// Tiny: exclusive scan of the 98 bucket totals -> global bucket bases; also off[N]=E.
__global__ __launch_bounds__(128) void bucket_scan_kernel(const int* __restrict__ bcur,
                                                          int* __restrict__ bbase,
                                                          int* __restrict__ off) {
    __shared__ int s[128];
    int tid = threadIdx.x;
    int v = (tid < NBUCK) ? bcur[tid] : 0;
    s[tid] = v;
    __syncthreads();
#pragma unroll
    for (int d = 1; d < 128; d <<= 1) {
        int t = (tid >= d) ? s[tid - d] : 0;
        __syncthreads();
        s[tid] += t;
        __syncthreads();
    }
    if (tid < NBUCK) bbase[tid] = s[tid] - v;   // exclusive
    if (tid == 0) off[N_NODES] = N_EDGES;
}

// Per-bucket (1024 nodes): LDS hist -> LDS scan -> write off -> LDS-atomic scatter to csr.
// Replaces hist_kernel (1.6M global atomics, 65us, 50MB atomic write traffic), the 3 scan
// kernels, and scatter2 (1.6M more global atomics). csr writes land in a contiguous
// ~64KB window per block (same L2-friendly pattern as the old sequential scatter).
__global__ __launch_bounds__(1024) void bucket_csr_kernel(const u64* __restrict__ ebuf,
                                                          const int* __restrict__ bcur,
                                                          const int* __restrict__ bbase,
                                                          int* __restrict__ off,
                                                          int* __restrict__ csr) {
    __shared__ int hist[1024];
    __shared__ int sc[1024];
    __shared__ int cnt[1024];
    int b = blockIdx.x;
    int tid = threadIdx.x;
    int nE = bcur[b];
    if (nE > CAP) nE = CAP;
    int base = bbase[b];
    const u64* slab = ebuf + (size_t)b * CAP;

    hist[tid] = 0;
    cnt[tid] = 0;
    __syncthreads();
    for (int i = tid; i < nE; i += 1024) {
        int d = (int)(slab[i] >> 32) & 1023;
        atomicAdd(&hist[d], 1);
    }
    __syncthreads();
    sc[tid] = hist[tid];
    __syncthreads();
#pragma unroll
    for (int d = 1; d < 1024; d <<= 1) {
        int t = (tid >= d) ? sc[tid - d] : 0;
        __syncthreads();
        sc[tid] += t;
        __syncthreads();
    }
    int excl = sc[tid] - hist[tid];
    sc[tid] = excl;   // reuse as exclusive scan
    int node = b * 1024 + tid;
    if (node < N_NODES) off[node] = base + excl;
    __syncthreads();
    for (int i = tid; i < nE; i += 1024) {
        u64 e = slab[i];
        int d = (int)(e >> 32) & 1023;
        int pos = sc[d] + atomicAdd(&cnt[d], 1);
        csr[base + pos] = (int)(e & 0xFFFFFFFFu);
    }
}

// Sort each node's adjacency list by src (ascending): one node per WAVE, bitonic
// sort across 64 lanes via shfl_xor (21 compare-exchange stages, no divergence,
// coalesced load/store). Replaces the R2 per-thread insertion sort that cost
// ~40-70us (serial O(deg^2) + 64-lane divergence). Sorted lists band the agg
// gather stream -> L2-resident instantaneous working set (R2: agg 70.7 -> <=65).
// deg > 64 (P ~ 1e-20 at mean 16): left unsorted, still correct.
__global__ __launch_bounds__(256) void sort_adj_kernel(const int* __restrict__ off,
                                                       int* __restrict__ csr) {
    int node = (blockIdx.x * 256 + threadIdx.x) >> 6;
    if (node >= N_NODES) return;
    int lane = threadIdx.x & 63;
    int s = off[node];
    int n = off[node + 1] - s;
    if (n <= 1 || n > 64) return;
    int v = (lane < n) ? csr[s + lane] : 0x7FFFFFFF;
#pragma unroll
    for (int k = 2; k <= 64; k <<= 1) {
#pragma unroll
        for (int j = k >> 1; j > 0; j >>= 1) {
            int o = __shfl_xor(v, j, 64);
            bool up = ((lane & k) == 0);
            bool keepmin = (((lane & j) == 0) == up);
            v = keepmin ? min(v, o) : max(v, o);
        }
    }
    if (lane < n) csr[s + lane] = v;
}

// ---------------- aggregation: t[i] = x[i] + sum_{j in N_in(i)} x[j]  (bf16 in/out) ----------------

__global__ __launch_bounds__(256) void agg_bf16(const unsigned int* __restrict__ xb,
                                                const int* __restrict__ off,
                                                const int* __restrict__ csr,
                                                unsigned int* __restrict__ t) {
    int node = blockIdx.x * 4 + (threadIdx.x >> 6);
    if (node >= N_NODES) return;
    int lane = threadIdx.x & 63;
    unsigned int v = xb[(size_t)node * 64 + lane];
    float ax = b2f_lo(v), ay = b2f_hi(v);
    int e = off[node + 1];
    int k = off[node];
    for (; k + 8 <= e; k += 8) {
        int n0 = csr[k + 0], n1 = csr[k + 1], n2 = csr[k + 2], n3 = csr[k + 3];
        int n4 = csr[k + 4], n5 = csr[k + 5], n6 = csr[k + 6], n7 = csr[k + 7];
        unsigned int g0 = xb[(size_t)n0 * 64 + lane];
        unsigned int g1 = xb[(size_t)n1 * 64 + lane];
        unsigned int g2 = xb[(size_t)n2 * 64 + lane];
        unsigned int g3 = xb[(size_t)n3 * 64 + lane];
        unsigned int g4 = xb[(size_t)n4 * 64 + lane];
        unsigned int g5 = xb[(size_t)n5 * 64 + lane];
        unsigned int g6 = xb[(size_t)n6 * 64 + lane];
        unsigned int g7 = xb[(size_t)n7 * 64 + lane];
        ax += b2f_lo(g0) + b2f_lo(g1) + b2f_lo(g2) + b2f_lo(g3)
            + b2f_lo(g4) + b2f_lo(g5) + b2f_lo(g6) + b2f_lo(g7);
        ay += b2f_hi(g0) + b2f_hi(g1) + b2f_hi(g2) + b2f_hi(g3)
            + b2f_hi(g4) + b2f_hi(g5) + b2f_hi(g6) + b2f_hi(g7);
    }
    if (k + 4 <= e) {
        int n0 = csr[k + 0], n1 = csr[k + 1], n2 = csr[k + 2], n3 = csr[k + 3];
        unsigned int g0 = xb[(size_t)n0 * 64 + lane];
        unsigned int g1 = xb[(size_t)n1 * 64 + lane];
        unsigned int g2 = xb[(size_t)n2 * 64 + lane];
        unsigned int g3 = xb[(size_t)n3 * 64 + lane];
        ax += b2f_lo(g0) + b2f_lo(g1) + b2f_lo(g2) + b2f_lo(g3);
        ay += b2f_hi(g0) + b2f_hi(g1) + b2f_hi(g2) + b2f_hi(g3);
        k += 4;
    }
    for (; k < e; k++) {
        unsigned int g = xb[(size_t)csr[k] * 64 + lane];
        ax += b2f_lo(g);
        ay += b2f_hi(g);
    }
    t[(size_t)node * 64 + lane] = (unsigned int)f2b(ax) | ((unsigned int)f2b(ay) << 16);
}

// ---------------- fused MLP: y = relu(relu(t @ W1 + b1) @ W2 + b2) ----------------
// 2 row-strips (32 rows) per wave: one W-fragment load feeds MFMAs of both strips,
// halving per-wave L2 weight traffic. Per-wave LDS 8704 B.

template <bool OUT_F32>
__global__ __launch_bounds__(256) void mlp_mfma(const unsigned short* __restrict__ A,
                                                const unsigned short* __restrict__ W1t,
                                                const float* __restrict__ bias1,
                                                const unsigned short* __restrict__ W2t,
                                                const float* __restrict__ bias2,
                                                void* __restrict__ out) {
    __shared__ char smem[4 * 8704];
    int tid = threadIdx.x;
    int wave = tid >> 6, lane = tid & 63;
    int quad = lane >> 4, mr = lane & 15;
    int m_base = blockIdx.x * 128 + wave * 32;
    int m0 = m_base + mr;       if (m0 >= N_NODES) m0 = N_NODES - 1;
    int m1 = m_base + 16 + mr;  if (m1 >= N_NODES) m1 = N_NODES - 1;

    unsigned short* ust = (unsigned short*)(smem + wave * 8704);  // strip0 @0, strip1 @2176 shorts

    // ---- GEMM1: u = relu(t @ W1 + b1), both strips ----
    bf16x8 a0[4], a1[4];
#pragma unroll
    for (int kc = 0; kc < 4; kc++) {
        a0[kc] = *(const bf16x8*)(A + (size_t)m0 * D + kc * 32 + quad * 8);
        a1[kc] = *(const bf16x8*)(A + (size_t)m1 * D + kc * 32 + quad * 8);
    }

    f32x4 acc0[8], acc1[8];
#pragma unroll
    for (int nt = 0; nt < 8; nt++) { acc0[nt] = (f32x4)0.0f; acc1[nt] = (f32x4)0.0f; }
#pragma unroll
    for (int nt = 0; nt < 8; nt++) {
        const unsigned short* wp = W1t + (size_t)(nt * 16 + mr) * D + quad * 8;
#pragma unroll
        for (int kc = 0; kc < 4; kc++) {
            bf16x8 b = *(const bf16x8*)(wp + kc * 32);
            acc0[nt] = __builtin_amdgcn_mfma_f32_16x16x32_bf16(a0[kc], b, acc0[nt], 0, 0, 0);
            acc1[nt] = __builtin_amdgcn_mfma_f32_16x16x32_bf16(a1[kc], b, acc1[nt], 0, 0, 0);
        }
    }
    // C layout: col(n) = mr, row(m in strip) = quad*4 + r
#pragma unroll
    for (int nt = 0; nt < 8; nt++) {
        float bv = bias1[nt * 16 + mr];
#pragma unroll
        for (int r = 0; r < 4; r++) {
            ust[(quad * 4 + r) * 136 + nt * 16 + mr] = f2b(fmaxf(acc0[nt][r] + bv, 0.0f));
            ust[2176 + (quad * 4 + r) * 136 + nt * 16 + mr] = f2b(fmaxf(acc1[nt][r] + bv, 0.0f));
        }
    }

    // ---- GEMM2: y = relu(u @ W2 + b2), both strips ----
#pragma unroll
    for (int kc = 0; kc < 4; kc++) {
        a0[kc] = *(const bf16x8*)&ust[mr * 136 + kc * 32 + quad * 8];
        a1[kc] = *(const bf16x8*)&ust[2176 + mr * 136 + kc * 32 + quad * 8];
    }
#pragma unroll
    for (int nt = 0; nt < 8; nt++) { acc0[nt] = (f32x4)0.0f; acc1[nt] = (f32x4)0.0f; }
#pragma unroll
    for (int nt = 0; nt < 8; nt++) {
        const unsigned short* wp = W2t + (size_t)(nt * 16 + mr) * D + quad * 8;
#pragma unroll
        for (int kc = 0; kc < 4; kc++) {
            bf16x8 b = *(const bf16x8*)(wp + kc * 32);
            acc0[nt] = __builtin_amdgcn_mfma_f32_16x16x32_bf16(a0[kc], b, acc0[nt], 0, 0, 0);
            acc1[nt] = __builtin_amdgcn_mfma_f32_16x16x32_bf16(a1[kc], b, acc1[nt], 0, 0, 0);
        }
    }

    // ---- epilogue: stage each strip in LDS, coalesced store (u-strips dead now) ----
    if (OUT_F32) {
        float* st = (float*)ust;   // 16 x 132 f32 = 8448 B, fits in the 8704 B wave region
        const int S = 132;
        float* op = (float*)out;
#pragma unroll
        for (int s = 0; s < 2; s++) {
#pragma unroll
            for (int nt = 0; nt < 8; nt++) {
                float bv = bias2[nt * 16 + mr];
#pragma unroll
                for (int r = 0; r < 4; r++) {
                    float v = s ? acc1[nt][r] : acc0[nt][r];
                    st[(quad * 4 + r) * S + nt * 16 + mr] = fmaxf(v + bv, 0.0f);
                }
            }
#pragma unroll
            for (int it = 0; it < 8; it++) {
                int linear = lane + it * 64;
                int row = linear >> 5, col = (linear & 31) << 2;
                int gm = m_base + s * 16 + row;
                if (gm < N_NODES) {
                    float4 val = *(float4*)&st[row * S + col];
                    *(float4*)(op + (size_t)gm * D + col) = val;
                }
            }
        }
    } else {
        const int S = 136;
        unsigned short* op = (unsigned short*)out;
#pragma unroll
        for (int s = 0; s < 2; s++) {
            unsigned short* st = ust + s * 2176;
#pragma unroll
            for (int nt = 0; nt < 8; nt++) {
                float bv = bias2[nt * 16 + mr];
#pragma unroll
                for (int r = 0; r < 4; r++) {
                    float v = s ? acc1[nt][r] : acc0[nt][r];
                    st[(quad * 4 + r) * S + nt * 16 + mr] = f2b(fmaxf(v + bv, 0.0f));
                }
            }
#pragma unroll
            for (int it = 0; it < 4; it++) {
                int linear = lane + it * 64;
                int row = linear >> 4, col = (linear & 15) << 3;
                int gm = m_base + s * 16 + row;
                if (gm < N_NODES) {
                    uint4 val = *(uint4*)&st[row * S + col];
                    *(uint4*)(op + (size_t)gm * D + col) = val;
                }
            }
        }
    }
}

// ---------------- launch ----------------

extern "C" void kernel_launch(void* const* d_in, const int* in_sizes, int n_in,
                              void* d_out, int out_size, void* d_ws, size_t ws_size,
                              hipStream_t stream) {
    const float* x = (const float*)d_in[0];
    const int* ei = (const int*)d_in[1];
    const int* srcv = ei;
    const int* dstv = ei + N_EDGES;
    const float* W1[3] = {(const float*)d_in[2], (const float*)d_in[6], (const float*)d_in[10]};
    const float* b1[3] = {(const float*)d_in[3], (const float*)d_in[7], (const float*)d_in[11]};
    const float* W2[3] = {(const float*)d_in[4], (const float*)d_in[8], (const float*)d_in[12]};
    const float* b2[3] = {(const float*)d_in[5], (const float*)d_in[9], (const float*)d_in[13]};

    // ws layout (high-water 58400256):
    char* ws = (char*)d_ws;
    int* off = (int*)ws;                                    // (N+1) ints
    unsigned short* Wt[6];                                  // 6 x 32KB @ 400128
    for (int i = 0; i < 6; i++) Wt[i] = (unsigned short*)(ws + 400128 + i * 32768);
    int* csr = (int*)(ws + 800256);                         // E ints (ends 7200256)
    unsigned short* xb = (unsigned short*)(ws + 7200256);   // N*D bf16 (ends 32800256)
    unsigned short* P  = (unsigned short*)(ws + 32800256);  // N*D bf16 (ends 58400256)

    // d_out scratch (dead before the final MLP overwrites all of d_out):
    char* dob = (char*)d_out;
    int* bcur  = (int*)(dob);               // NBUCK ints (zeroed by prep)
    int* bbase = (int*)(dob + 512);         // NBUCK ints (written by bucket_scan)
    u64* ebuf  = (u64*)(dob + 1048576);     // NBUCK*CAP u64 = 16.06MB (< 51.2MB d_out)

    // --- prep: zero bcur + convert weights + convert x ---
    prep_kernel<<<12885, 256, 0, stream>>>(
        x, xb,
        W1[0], W2[0], W1[1], W2[1], W1[2], W2[2],
        Wt[0], Wt[1], Wt[2], Wt[3], Wt[4], Wt[5],
        (uint4*)dob);

    // --- CSR build (bucket-local, no global atomics in the hot paths) ---
    bin_kernel<<<782, 256, 0, stream>>>(srcv, dstv, bcur, ebuf);
    bucket_scan_kernel<<<1, 128, 0, stream>>>(bcur, bbase, off);
    bucket_csr_kernel<<<NBUCK, 1024, 0, stream>>>(ebuf, bcur, bbase, off, csr);
    sort_adj_kernel<<<25000, 256, 0, stream>>>(off, csr);

    const int agg_grid = 25000;                        // 4 nodes/block
    const int mlp_grid = (N_NODES + 127) / 128;        // 782 (2 strips/wave)

    // layer 0: agg xb->P, mlp P->xb
    agg_bf16<<<agg_grid, 256, 0, stream>>>((const unsigned int*)xb, off, csr, (unsigned int*)P);
    mlp_mfma<false><<<mlp_grid, 256, 0, stream>>>(P, Wt[0], b1[0], Wt[1], b2[0], xb);
    // layer 1
    agg_bf16<<<agg_grid, 256, 0, stream>>>((const unsigned int*)xb, off, csr, (unsigned int*)P);
    mlp_mfma<false><<<mlp_grid, 256, 0, stream>>>(P, Wt[2], b1[1], Wt[3], b2[1], xb);
    // layer 2
    agg_bf16<<<agg_grid, 256, 0, stream>>>((const unsigned int*)xb, off, csr, (unsigned int*)P);
    mlp_mfma<true><<<mlp_grid, 256, 0, stream>>>(P, Wt[4], b1[2], Wt[5], b2[2], d_out);
}

// Round 4
// 504.947 us; speedup vs baseline: 1.2936x; 1.0491x over previous
//
#include <hip/hip_runtime.h>

#define N_NODES 100000
#define N_EDGES 1600000
#define D 128
#define NBUCK 98          // ceil(N_NODES / 1024), bucket = dst >> 10
#define CAP 20480         // ebuf slab capacity per bucket (raw edges); mean 16384, sigma~127

typedef __attribute__((ext_vector_type(8))) short bf16x8;
typedef __attribute__((ext_vector_type(4))) float f32x4;
typedef unsigned long long u64;

__device__ __forceinline__ float b2f_lo(unsigned int u) {
    return __builtin_bit_cast(float, u << 16);
}
__device__ __forceinline__ float b2f_hi(unsigned int u) {
    return __builtin_bit_cast(float, u & 0xFFFF0000u);
}
__device__ __forceinline__ unsigned short f2b(float f) {
    unsigned int u = __builtin_bit_cast(unsigned int, f);
    u += 0x7FFFu + ((u >> 16) & 1u);
    return (unsigned short)(u >> 16);
}

// ---------------- prep: zero scratch + convert weights + convert x + zero sentinel row ----------------

__global__ __launch_bounds__(256) void prep_kernel(
    const float* __restrict__ x, unsigned short* __restrict__ xb,
    const float* __restrict__ W0, const float* __restrict__ W1_, const float* __restrict__ W2_,
    const float* __restrict__ W3, const float* __restrict__ W4, const float* __restrict__ W5,
    unsigned short* __restrict__ T0, unsigned short* __restrict__ T1_,
    unsigned short* __restrict__ T2_, unsigned short* __restrict__ T3,
    unsigned short* __restrict__ T4, unsigned short* __restrict__ T5,
    uint4* __restrict__ dob4, uint4* __restrict__ xbs4) {
    int blk = blockIdx.x;
    if (blk < 384) {
        const float* W;
        unsigned short* T;
        switch (blk >> 6) {
            case 0: W = W0; T = T0; break;
            case 1: W = W1_; T = T1_; break;
            case 2: W = W2_; T = T2_; break;
            case 3: W = W3; T = T3; break;
            case 4: W = W4; T = T4; break;
            default: W = W5; T = T5; break;
        }
        int i = (blk & 63) * 256 + threadIdx.x;   // 0..16383
        int k = i >> 7, n = i & 127;
        T[n * 128 + k] = f2b(W[i]);               // [k][n] fp32 -> [n][k] bf16
    } else if (blk < 12884) {
        int i = (blk - 384) * 256 + threadIdx.x;  // float4 chunks, 3200000 total
        if (i < 3200000) {
            float4 v = ((const float4*)x)[i];
            ushort4 o;
            o.x = f2b(v.x); o.y = f2b(v.y); o.z = f2b(v.z); o.w = f2b(v.w);
            ((ushort4*)xb)[i] = o;
        }
    } else {
        int i = (blk - 12884) * 256 + threadIdx.x;
        uint4 z = {0u, 0u, 0u, 0u};
        if (i < 256) dob4[i] = z;     // zero d_out scratch head [0, 4096) = bcur
        if (i < 16) xbs4[i] = z;      // zero sentinel row xb[N_NODES] (gather target of pads)
    }
}

// ---------------- CSR build (bucket-local, LDS atomics only, padded degrees) ----------------

// Bin edges into fixed-stride bucket slabs: slab b = ebuf[b*CAP ...].
__global__ __launch_bounds__(256) void bin_kernel(const int* __restrict__ src,
                                                  const int* __restrict__ dst,
                                                  int* __restrict__ bcur,
                                                  u64* __restrict__ ebuf) {
    __shared__ int h[NBUCK];
    __shared__ int base[NBUCK];
    int tid = threadIdx.x;
    if (tid < NBUCK) h[tid] = 0;
    __syncthreads();
    int e0 = blockIdx.x * 2048;
    int myd[8], mys[8];
#pragma unroll
    for (int i = 0; i < 8; i++) {
        int e = e0 + tid + i * 256;
        int dv = (e < N_EDGES) ? dst[e] : -1;
        myd[i] = dv;
        mys[i] = (e < N_EDGES) ? src[e] : 0;
        if (dv >= 0) atomicAdd(&h[dv >> 10], 1);
    }
    __syncthreads();
    if (tid < NBUCK) {
        int c = h[tid];
        base[tid] = (c > 0) ? (tid * CAP + atomicAdd(&bcur[tid], c)) : 0;
        h[tid] = 0;
    }
    __syncthreads();
#pragma unroll
    for (int i = 0; i < 8; i++) {
        int dv = myd[i];
        if (dv >= 0) {
            int b = dv >> 10;
            int p = base[b] + atomicAdd(&h[b], 1);
            if (p < (b + 1) * CAP)
                ebuf[p] = ((u64)(unsigned int)dv << 32) | (unsigned int)mys[i];
        }
    }
}

// Per-bucket: LDS hist of dst -> per-node deg (global) + padded bucket total.
__global__ __launch_bounds__(1024) void bucket_hist_kernel(const u64* __restrict__ ebuf,
                                                           const int* __restrict__ bcur,
                                                           int* __restrict__ deg,
                                                           int* __restrict__ ptot) {
    __shared__ int hist[1024];
    int b = blockIdx.x, tid = threadIdx.x;
    int nE = bcur[b]; if (nE > CAP) nE = CAP;
    const u64* slab = ebuf + (size_t)b * CAP;
    hist[tid] = 0;
    __syncthreads();
    for (int i = tid; i < nE; i += 1024)
        atomicAdd(&hist[(int)(slab[i] >> 32) & 1023], 1);
    __syncthreads();
    int node = b * 1024 + tid;
    int d = hist[tid];
    if (node < N_NODES) deg[node] = d;
    int dp = (node < N_NODES) ? ((d + 3) & ~3) : 0;
    __syncthreads();
    hist[tid] = dp;
    __syncthreads();
#pragma unroll
    for (int s = 512; s > 0; s >>= 1) {
        if (tid < s) hist[tid] += hist[tid + s];
        __syncthreads();
    }
    if (tid == 0) ptot[b] = hist[0];
}

// Exclusive scan of the 98 padded bucket totals; off[N] = padded grand total.
__global__ __launch_bounds__(128) void pscan_kernel(const int* __restrict__ ptot,
                                                    int* __restrict__ bbase,
                                                    int* __restrict__ off) {
    __shared__ int s[128];
    int tid = threadIdx.x;
    int v = (tid < NBUCK) ? ptot[tid] : 0;
    s[tid] = v;
    __syncthreads();
#pragma unroll
    for (int d = 1; d < 128; d <<= 1) {
        int t = (tid >= d) ? s[tid - d] : 0;
        __syncthreads();
        s[tid] += t;
        __syncthreads();
    }
    if (tid < NBUCK) bbase[tid] = s[tid] - v;
    if (tid == 127) off[N_NODES] = s[127];
}

// Per-bucket: padded LDS scan of deg -> off, LDS-atomic scatter into globally
// contiguous padded CSR, pad slots = sentinel N_NODES (zero row in xb).
// Padding to %4 lets agg run pure 4-edge gather instructions, no scalar tail.
__global__ __launch_bounds__(1024) void bucket_csr_kernel(const u64* __restrict__ ebuf,
                                                          const int* __restrict__ bcur,
                                                          const int* __restrict__ deg,
                                                          const int* __restrict__ bbase,
                                                          int* __restrict__ off,
                                                          int* __restrict__ csr) {
    __shared__ int sc[1024];
    __shared__ int cnt[1024];
    int b = blockIdx.x, tid = threadIdx.x;
    int nE = bcur[b]; if (nE > CAP) nE = CAP;
    int base = bbase[b];
    const u64* slab = ebuf + (size_t)b * CAP;
    int node = b * 1024 + tid;
    int d = (node < N_NODES) ? deg[node] : 0;
    int dp = (node < N_NODES) ? ((d + 3) & ~3) : 0;
    sc[tid] = dp;
    cnt[tid] = 0;
    __syncthreads();
#pragma unroll
    for (int s = 1; s < 1024; s <<= 1) {
        int t = (tid >= s) ? sc[tid - s] : 0;
        __syncthreads();
        sc[tid] += t;
        __syncthreads();
    }
    int excl = sc[tid] - dp;
    sc[tid] = excl;
    if (node < N_NODES) off[node] = base + excl;
    __syncthreads();
    for (int i = tid; i < nE; i += 1024) {
        u64 e = slab[i];
        int dd = (int)(e >> 32) & 1023;
        int pos = sc[dd] + atomicAdd(&cnt[dd], 1);
        csr[base + pos] = (int)(e & 0xFFFFFFFFu);
    }
    for (int j = d; j < dp; j++) csr[base + excl + j] = N_NODES;  // <=3 pads/node
}

// ---------------- aggregation: t[i] = x[i] + sum_{j in N_in(i)} x[j]  (bf16 in/out) ----------------
// 4 edges per VMEM instruction: lane = (edge-slot g = lane>>4, column c = lane&15),
// each lane loads uint4 (16 B) -> one instruction gathers 4 full 256 B rows (1 KB).
// 4x in-flight gather bytes per wave vs the dword version (latency-bound regime:
// VALUBusy 38%, FETCH at the 8-XCD compulsory floor, no pipe saturated).
// Padded CSR guarantees (e - k) % 4 == 0; sentinel rows read zeros (L1-resident).

__global__ __launch_bounds__(256) void agg_bf16(const uint4* __restrict__ xb4,
                                                const int* __restrict__ off,
                                                const int* __restrict__ csr,
                                                uint4* __restrict__ t4) {
    int node = blockIdx.x * 4 + (threadIdx.x >> 6);
    if (node >= N_NODES) return;
    int lane = threadIdx.x & 63;
    int g = lane >> 4;
    int c = lane & 15;
    uint4 me = xb4[(size_t)node * 16 + c];
    float w0 = (g == 0) ? 1.0f : 0.0f;    // self term counted once across groups
    float a0 = b2f_lo(me.x) * w0, a1 = b2f_hi(me.x) * w0;
    float a2 = b2f_lo(me.y) * w0, a3 = b2f_hi(me.y) * w0;
    float a4 = b2f_lo(me.z) * w0, a5 = b2f_hi(me.z) * w0;
    float a6 = b2f_lo(me.w) * w0, a7 = b2f_hi(me.w) * w0;
    int k = off[node], e = off[node + 1];
#define PICK4(q) ((g & 2) ? ((g & 1) ? (q).w : (q).z) : ((g & 1) ? (q).y : (q).x))
#define ACC8(v) { a0 += b2f_lo((v).x); a1 += b2f_hi((v).x); \
                  a2 += b2f_lo((v).y); a3 += b2f_hi((v).y); \
                  a4 += b2f_lo((v).z); a5 += b2f_hi((v).z); \
                  a6 += b2f_lo((v).w); a7 += b2f_hi((v).w); }
    for (; k + 16 <= e; k += 16) {
        int4 q0 = *(const int4*)(csr + k);
        int4 q1 = *(const int4*)(csr + k + 4);
        int4 q2 = *(const int4*)(csr + k + 8);
        int4 q3 = *(const int4*)(csr + k + 12);
        int n0 = PICK4(q0), n1 = PICK4(q1), n2 = PICK4(q2), n3 = PICK4(q3);
        uint4 v0 = xb4[(size_t)n0 * 16 + c];
        uint4 v1 = xb4[(size_t)n1 * 16 + c];
        uint4 v2 = xb4[(size_t)n2 * 16 + c];
        uint4 v3 = xb4[(size_t)n3 * 16 + c];
        ACC8(v0); ACC8(v1); ACC8(v2); ACC8(v3);
    }
    for (; k < e; k += 4) {
        int4 q = *(const int4*)(csr + k);
        int n = PICK4(q);
        uint4 v = xb4[(size_t)n * 16 + c];
        ACC8(v);
    }
#undef PICK4
#undef ACC8
    // combine the 4 edge-groups: each column slice c exists in lanes c, c+16, c+32, c+48
    a0 += __shfl_xor(a0, 16); a1 += __shfl_xor(a1, 16);
    a2 += __shfl_xor(a2, 16); a3 += __shfl_xor(a3, 16);
    a4 += __shfl_xor(a4, 16); a5 += __shfl_xor(a5, 16);
    a6 += __shfl_xor(a6, 16); a7 += __shfl_xor(a7, 16);
    a0 += __shfl_xor(a0, 32); a1 += __shfl_xor(a1, 32);
    a2 += __shfl_xor(a2, 32); a3 += __shfl_xor(a3, 32);
    a4 += __shfl_xor(a4, 32); a5 += __shfl_xor(a5, 32);
    a6 += __shfl_xor(a6, 32); a7 += __shfl_xor(a7, 32);
    if (g == 0) {
        uint4 o;
        o.x = (unsigned int)f2b(a0) | ((unsigned int)f2b(a1) << 16);
        o.y = (unsigned int)f2b(a2) | ((unsigned int)f2b(a3) << 16);
        o.z = (unsigned int)f2b(a4) | ((unsigned int)f2b(a5) << 16);
        o.w = (unsigned int)f2b(a6) | ((unsigned int)f2b(a7) << 16);
        t4[(size_t)node * 16 + c] = o;
    }
}

// ---------------- fused MLP: y = relu(relu(t @ W1 + b1) @ W2 + b2) ----------------
// 2 row-strips (32 rows) per wave: one W-fragment load feeds MFMAs of both strips,
// halving per-wave L2 weight traffic. Per-wave LDS 8704 B.

template <bool OUT_F32>
__global__ __launch_bounds__(256) void mlp_mfma(const unsigned short* __restrict__ A,
                                                const unsigned short* __restrict__ W1t,
                                                const float* __restrict__ bias1,
                                                const unsigned short* __restrict__ W2t,
                                                const float* __restrict__ bias2,
                                                void* __restrict__ out) {
    __shared__ char smem[4 * 8704];
    int tid = threadIdx.x;
    int wave = tid >> 6, lane = tid & 63;
    int quad = lane >> 4, mr = lane & 15;
    int m_base = blockIdx.x * 128 + wave * 32;
    int m0 = m_base + mr;       if (m0 >= N_NODES) m0 = N_NODES - 1;
    int m1 = m_base + 16 + mr;  if (m1 >= N_NODES) m1 = N_NODES - 1;

    unsigned short* ust = (unsigned short*)(smem + wave * 8704);  // strip0 @0, strip1 @2176 shorts

    // ---- GEMM1: u = relu(t @ W1 + b1), both strips ----
    bf16x8 a0[4], a1[4];
#pragma unroll
    for (int kc = 0; kc < 4; kc++) {
        a0[kc] = *(const bf16x8*)(A + (size_t)m0 * D + kc * 32 + quad * 8);
        a1[kc] = *(const bf16x8*)(A + (size_t)m1 * D + kc * 32 + quad * 8);
    }

    f32x4 acc0[8], acc1[8];
#pragma unroll
    for (int nt = 0; nt < 8; nt++) { acc0[nt] = (f32x4)0.0f; acc1[nt] = (f32x4)0.0f; }
#pragma unroll
    for (int nt = 0; nt < 8; nt++) {
        const unsigned short* wp = W1t + (size_t)(nt * 16 + mr) * D + quad * 8;
#pragma unroll
        for (int kc = 0; kc < 4; kc++) {
            bf16x8 b = *(const bf16x8*)(wp + kc * 32);
            acc0[nt] = __builtin_amdgcn_mfma_f32_16x16x32_bf16(a0[kc], b, acc0[nt], 0, 0, 0);
            acc1[nt] = __builtin_amdgcn_mfma_f32_16x16x32_bf16(a1[kc], b, acc1[nt], 0, 0, 0);
        }
    }
    // C layout: col(n) = mr, row(m in strip) = quad*4 + r
#pragma unroll
    for (int nt = 0; nt < 8; nt++) {
        float bv = bias1[nt * 16 + mr];
#pragma unroll
        for (int r = 0; r < 4; r++) {
            ust[(quad * 4 + r) * 136 + nt * 16 + mr] = f2b(fmaxf(acc0[nt][r] + bv, 0.0f));
            ust[2176 + (quad * 4 + r) * 136 + nt * 16 + mr] = f2b(fmaxf(acc1[nt][r] + bv, 0.0f));
        }
    }

    // ---- GEMM2: y = relu(u @ W2 + b2), both strips ----
#pragma unroll
    for (int kc = 0; kc < 4; kc++) {
        a0[kc] = *(const bf16x8*)&ust[mr * 136 + kc * 32 + quad * 8];
        a1[kc] = *(const bf16x8*)&ust[2176 + mr * 136 + kc * 32 + quad * 8];
    }
#pragma unroll
    for (int nt = 0; nt < 8; nt++) { acc0[nt] = (f32x4)0.0f; acc1[nt] = (f32x4)0.0f; }
#pragma unroll
    for (int nt = 0; nt < 8; nt++) {
        const unsigned short* wp = W2t + (size_t)(nt * 16 + mr) * D + quad * 8;
#pragma unroll
        for (int kc = 0; kc < 4; kc++) {
            bf16x8 b = *(const bf16x8*)(wp + kc * 32);
            acc0[nt] = __builtin_amdgcn_mfma_f32_16x16x32_bf16(a0[kc], b, acc0[nt], 0, 0, 0);
            acc1[nt] = __builtin_amdgcn_mfma_f32_16x16x32_bf16(a1[kc], b, acc1[nt], 0, 0, 0);
        }
    }

    // ---- epilogue: stage each strip in LDS, coalesced store (u-strips dead now) ----
    if (OUT_F32) {
        float* st = (float*)ust;   // 16 x 132 f32 = 8448 B, fits in the 8704 B wave region
        const int S = 132;
        float* op = (float*)out;
#pragma unroll
        for (int s = 0; s < 2; s++) {
#pragma unroll
            for (int nt = 0; nt < 8; nt++) {
                float bv = bias2[nt * 16 + mr];
#pragma unroll
                for (int r = 0; r < 4; r++) {
                    float v = s ? acc1[nt][r] : acc0[nt][r];
                    st[(quad * 4 + r) * S + nt * 16 + mr] = fmaxf(v + bv, 0.0f);
                }
            }
#pragma unroll
            for (int it = 0; it < 8; it++) {
                int linear = lane + it * 64;
                int row = linear >> 5, col = (linear & 31) << 2;
                int gm = m_base + s * 16 + row;
                if (gm < N_NODES) {
                    float4 val = *(float4*)&st[row * S + col];
                    *(float4*)(op + (size_t)gm * D + col) = val;
                }
            }
        }
    } else {
        const int S = 136;
        unsigned short* op = (unsigned short*)out;
#pragma unroll
        for (int s = 0; s < 2; s++) {
            unsigned short* st = ust + s * 2176;
#pragma unroll
            for (int nt = 0; nt < 8; nt++) {
                float bv = bias2[nt * 16 + mr];
#pragma unroll
                for (int r = 0; r < 4; r++) {
                    float v = s ? acc1[nt][r] : acc0[nt][r];
                    st[(quad * 4 + r) * S + nt * 16 + mr] = f2b(fmaxf(v + bv, 0.0f));
                }
            }
#pragma unroll
            for (int it = 0; it < 4; it++) {
                int linear = lane + it * 64;
                int row = linear >> 4, col = (linear & 15) << 3;
                int gm = m_base + s * 16 + row;
                if (gm < N_NODES) {
                    uint4 val = *(uint4*)&st[row * S + col];
                    *(uint4*)(op + (size_t)gm * D + col) = val;
                }
            }
        }
    }
}

// ---------------- launch ----------------

extern "C" void kernel_launch(void* const* d_in, const int* in_sizes, int n_in,
                              void* d_out, int out_size, void* d_ws, size_t ws_size,
                              hipStream_t stream) {
    const float* x = (const float*)d_in[0];
    const int* ei = (const int*)d_in[1];
    const int* srcv = ei;
    const int* dstv = ei + N_EDGES;
    const float* W1[3] = {(const float*)d_in[2], (const float*)d_in[6], (const float*)d_in[10]};
    const float* b1[3] = {(const float*)d_in[3], (const float*)d_in[7], (const float*)d_in[11]};
    const float* W2[3] = {(const float*)d_in[4], (const float*)d_in[8], (const float*)d_in[12]};
    const float* b2[3] = {(const float*)d_in[5], (const float*)d_in[9], (const float*)d_in[13]};

    // ws layout (high-water 59,398,400):
    char* ws = (char*)d_ws;
    int* off = (int*)ws;                                    // (N+1) ints @ 0
    unsigned short* Wt[6];                                  // 6 x 32KB @ 401,408
    for (int i = 0; i < 6; i++) Wt[i] = (unsigned short*)(ws + 401408 + i * 32768);
    int* csr = (int*)(ws + 598016);                         // padded CSR <= E+3N ints = 7.6MB
    unsigned short* xb = (unsigned short*)(ws + 8198144);   // (N+1)*D bf16 (sentinel row N)
    unsigned short* P  = (unsigned short*)(ws + 33798400);  // N*D bf16

    // d_out scratch (dead before the final MLP overwrites all of d_out):
    char* dob = (char*)d_out;
    int* bcur  = (int*)(dob);               // NBUCK ints (zeroed by prep)
    int* deg   = (int*)(dob + 4096);        // N ints
    int* ptot  = (int*)(dob + 450560);      // NBUCK ints
    int* bbase = (int*)(dob + 454656);      // NBUCK ints
    u64* ebuf  = (u64*)(dob + 1048576);     // NBUCK*CAP u64 = 16.06MB

    // --- prep: zero bcur + sentinel row + convert weights + convert x ---
    prep_kernel<<<12885, 256, 0, stream>>>(
        x, xb,
        W1[0], W2[0], W1[1], W2[1], W1[2], W2[2],
        Wt[0], Wt[1], Wt[2], Wt[3], Wt[4], Wt[5],
        (uint4*)dob, (uint4*)(xb + (size_t)N_NODES * D));

    // --- CSR build (bucket-local, padded to %4 per node) ---
    bin_kernel<<<782, 256, 0, stream>>>(srcv, dstv, bcur, ebuf);
    bucket_hist_kernel<<<NBUCK, 1024, 0, stream>>>(ebuf, bcur, deg, ptot);
    pscan_kernel<<<1, 128, 0, stream>>>(ptot, bbase, off);
    bucket_csr_kernel<<<NBUCK, 1024, 0, stream>>>(ebuf, bcur, deg, bbase, off, csr);

    const int agg_grid = 25000;                        // 4 nodes/block, 1 node/wave
    const int mlp_grid = (N_NODES + 127) / 128;        // 782 (2 strips/wave)

    // layer 0: agg xb->P, mlp P->xb
    agg_bf16<<<agg_grid, 256, 0, stream>>>((const uint4*)xb, off, csr, (uint4*)P);
    mlp_mfma<false><<<mlp_grid, 256, 0, stream>>>(P, Wt[0], b1[0], Wt[1], b2[0], xb);
    // layer 1
    agg_bf16<<<agg_grid, 256, 0, stream>>>((const uint4*)xb, off, csr, (uint4*)P);
    mlp_mfma<false><<<mlp_grid, 256, 0, stream>>>(P, Wt[2], b1[1], Wt[3], b2[1], xb);
    // layer 2
    agg_bf16<<<agg_grid, 256, 0, stream>>>((const uint4*)xb, off, csr, (uint4*)P);
    mlp_mfma<true><<<mlp_grid, 256, 0, stream>>>(P, Wt[4], b1[2], Wt[5], b2[2], d_out);
}